// Round 8
// baseline (74.077 us; speedup 1.0000x reference)
//
#include <hip/hip_runtime.h>
#include <hip/hip_cooperative_groups.h>
#include <hip/hip_bf16.h>
#include <float.h>

namespace cg = cooperative_groups;

// MeshLoss: out = mean_b,m( min_n |pc[b,m]-top[b,n]|^2 ) + mean((bottom-fem_bottom)^2)
// network_mesh (4,3,32,16,32) f32, pc (4,3,16384) f32, fem_mesh (4,3,32,16,32) f32.
// top[b,n] = network_mesh[b,:, n>>5, 15, n&31], n in [0,1024)
//
// |p-t|^2 = |p|^2 + (|t|^2 - 2 p.t): d' = fma(-2px,tx, fma(-2py,ty,
// fma(-2pz,tz, t2))) = 3 FMA/pair, pairs folded via v_min3_f32 -> 3.5 VALU/pair.
//
// R7 post-mortem: K1 was LDS-pipe-bound (1024 broadcast ds_read_b128/CU ~5.1us
// > VALU floor ~3.0us). Tops are wave-uniform -> fetch them on the SCALAR path:
// wave w (readfirstlane-uniform) reads its 128 tops (4 rows x 32) straight from
// global via uniform 32B-aligned group loads (s_load_dwordx8 expected; worst
// case one L1-hit fetch per wave). LDS pipe now carries only the 8KB pm
// combine. Single cooperative dispatch; grid.sync; block 0 does the final
// fixed-order sum. No atomics, fully deterministic.

#define NM_BATCH_STRIDE 49152     // 3*32*16*32 (== pc batch stride)
#define CH_STRIDE       16384
#define NBLK            256
#define NTHR            512
#define FEM_PER_BLK     180       // 46080 float4 pairs / 256 blocks

__global__ __launch_bounds__(NTHR) void meshloss_fused(
    const float* __restrict__ nm,
    const float* __restrict__ pc,
    const float* __restrict__ fem,
    float* __restrict__ ws,
    float* __restrict__ out)
{
    __shared__ float pm[8 * 256];      // per-wave partial mins
    __shared__ float wsum[8];

    const int t     = threadIdx.x;
    const int b     = blockIdx.x >> 6;      // batch
    const int chunk = blockIdx.x & 63;      // 256-point chunk
    const int w     = __builtin_amdgcn_readfirstlane(t >> 6);  // wave 0..7 (uniform)
    const int l     = t & 63;               // lane

    // ---- this lane's 4 points (same 4 points in every wave) ----
    const float* pcb = pc + b * NM_BATCH_STRIDE;
    const int m0 = chunk * 256 + l;                  // point p_j = l + j*64
    float px2[4], py2[4], pz2[4], pp[4], mn[4];
    #pragma unroll
    for (int j = 0; j < 4; ++j) {
        const int m = m0 + j * 64;
        float x = pcb[m];
        float y = pcb[CH_STRIDE + m];
        float z = pcb[2 * CH_STRIDE + m];
        pp[j]  = x * x + y * y + z * z;
        px2[j] = -2.0f * x;
        py2[j] = -2.0f * y;
        pz2[j] = -2.0f * z;
        mn[j]  = FLT_MAX;
    }

    // ---- wave w scans its 128 tops (rows 4w..4w+3, 32 tops each) ----
    // Row i: x at nmb[i*512+480 + k], y at +CH, z at +2CH (k=0..31).
    // Groups of 8: 32B-aligned contiguous, wave-uniform address -> scalar loads.
    const float* nmb = nm + b * NM_BATCH_STRIDE;
    #pragma unroll
    for (int rr = 0; rr < 4; ++rr) {
        const float* bx = nmb + (4 * w + rr) * 512 + 480;
        #pragma unroll
        for (int g = 0; g < 4; ++g) {
            float tx[8], ty[8], tz[8], t2[8];
            #pragma unroll
            for (int e = 0; e < 8; ++e) {
                tx[e] = bx[g * 8 + e];
                ty[e] = bx[CH_STRIDE + g * 8 + e];
                tz[e] = bx[2 * CH_STRIDE + g * 8 + e];
                t2[e] = tx[e] * tx[e] + ty[e] * ty[e] + tz[e] * tz[e];
            }
            #pragma unroll
            for (int j = 0; j < 4; ++j) {
                #define DISTD(e) __builtin_fmaf(px2[j], tx[e], \
                                 __builtin_fmaf(py2[j], ty[e], \
                                 __builtin_fmaf(pz2[j], tz[e], t2[e])))
                float d0 = DISTD(0);
                float d1 = DISTD(1);
                float d2 = DISTD(2);
                float d3 = DISTD(3);
                float d4 = DISTD(4);
                float d5 = DISTD(5);
                float d6 = DISTD(6);
                float d7 = DISTD(7);
                #undef DISTD
                mn[j] = fminf(mn[j], fminf(d0, d1));   // v_min3_f32
                mn[j] = fminf(mn[j], fminf(d2, d3));
                mn[j] = fminf(mn[j], fminf(d4, d5));
                mn[j] = fminf(mn[j], fminf(d6, d7));
            }
        }
    }

    // ---- per-wave partial (+|p|^2, commutes with cross-wave min) ----
    #pragma unroll
    for (int j = 0; j < 4; ++j)
        pm[w * 256 + l + j * 64] = mn[j] + pp[j];
    __syncthreads();

    // ---- 8-way min combine (threads 0..255) ----
    float v = 0.0f;
    if (t < 256) {
        float d = pm[t];
        #pragma unroll
        for (int ww = 1; ww < 8; ++ww)
            d = fminf(d, pm[ww * 256 + t]);
        v = d * (1.0f / 65536.0f);
    }

    // ---- fem MSE slice: 180 float4 pairs per block ----
    if (t < FEM_PER_BLK) {
        const int q   = blockIdx.x * FEM_PER_BLK + t;   // < 46080
        const int bci = q / 120;
        const int r   = q - bci * 120;
        const int s   = bci * 128 + r;
        float4 a = reinterpret_cast<const float4*>(nm)[s];
        float4 f = reinterpret_cast<const float4*>(fem)[s];
        float dx = a.x - f.x, dy = a.y - f.y, dz = a.z - f.z, dw = a.w - f.w;
        v += (dx * dx + dy * dy + dz * dz + dw * dw) * (1.0f / 184320.0f);
    }

    // ---- block reduce (8 waves) + plain store of block partial ----
    for (int o = 32; o > 0; o >>= 1) v += __shfl_down(v, o, 64);
    if (l == 0) wsum[w] = v;
    __syncthreads();
    if (t == 0) {
        float s = 0.0f;
        #pragma unroll
        for (int ww = 0; ww < 8; ++ww) s += wsum[ww];
        ws[blockIdx.x] = s;
    }

    // ---- grid-wide sync, then block 0 sums the 256 partials (fixed order) ----
    __threadfence();                 // device-scope visibility across XCDs
    cg::this_grid().sync();

    if (blockIdx.x == 0) {
        float fv = (t < 256) ? ws[t] : 0.0f;
        for (int o = 32; o > 0; o >>= 1) fv += __shfl_down(fv, o, 64);
        if (l == 0) wsum[w] = fv;
        __syncthreads();
        if (t == 0) {
            float s = 0.0f;
            #pragma unroll
            for (int ww = 0; ww < 8; ++ww) s += wsum[ww];
            out[0] = s;
        }
    }
}

extern "C" void kernel_launch(void* const* d_in, const int* in_sizes, int n_in,
                              void* d_out, int out_size, void* d_ws, size_t ws_size,
                              hipStream_t stream) {
    const float* nm  = (const float*)d_in[0];
    const float* pc  = (const float*)d_in[1];
    const float* fem = (const float*)d_in[2];
    float* out = (float*)d_out;
    float* ws  = (float*)d_ws;

    void* args[] = { (void*)&nm, (void*)&pc, (void*)&fem, (void*)&ws, (void*)&out };
    hipLaunchCooperativeKernel((void*)meshloss_fused, dim3(NBLK), dim3(NTHR),
                               args, 0, stream);
}

// Round 9
// 14.268 us; speedup vs baseline: 5.1917x; 5.1917x over previous
//
#include <hip/hip_runtime.h>
#include <hip/hip_bf16.h>
#include <float.h>

// MeshLoss: out = mean_b,m( min_n |pc[b,m]-top[b,n]|^2 ) + mean((bottom-fem_bottom)^2)
// network_mesh (4,3,32,16,32) f32, pc (4,3,16384) f32, fem_mesh (4,3,32,16,32) f32.
// top[b,n] = network_mesh[b,:, n>>5, 15, n&31], n in [0,1024)
//
// |p-t|^2 = |p|^2 + (|t|^2 - 2 p.t): d' = fma(-2px,tx, fma(-2py,ty,
// fma(-2pz,tz, t2))) = 3 FMA/pair, folded pairwise into v_min3_f32.
//
// R8 post-mortem: scalar-unit top fetch is an ISA dead end (no scalar float
// ALU; 1-SGPR-operand limit forces v_mov fan-out) and cg grid sync spins.
// Reverted to R7's proven structure. R9 delta: SoA top staging WITHOUT |t|^2
// (xs/ys/zs float arrays, float4 reads = 4 tops/read -> 6 ds_read_b128 per
// 8 tops instead of 8; t2 recomputed once per 8-top group). K1 becomes
// VALU-bound (~3.6us model). K2 shrunk to a single wave.
//
// K1: 256 blocks x 512 thr (1 block/CU). Block = (batch, 256-pt chunk).
//     8 waves PARTITION the 1024 tops (128 each); every wave covers all 256
//     block points (4/lane). Per-wave mins (+|p|^2) -> pm[8][256] -> 8-way
//     min by t<256; fem slice (180 float4 pairs) folded in; block partial
//     -> ws[block] (plain store).
// K2: 1 wave: fixed-order sum of 256 partials -> out[0]. No atomics anywhere.

#define NM_BATCH_STRIDE 49152     // 3*32*16*32 (== pc batch stride)
#define CH_STRIDE       16384
#define NTOP            1024
#define TOPS_PER_WAVE   128       // 1024 / 8 waves
#define NBLK            256
#define NTHR            512
#define FEM_PER_BLK     180       // 46080 float4 pairs / 256 blocks

__global__ __launch_bounds__(NTHR) void meshloss_fused(
    const float* __restrict__ nm,
    const float* __restrict__ pc,
    const float* __restrict__ fem,
    float* __restrict__ ws)
{
    __shared__ __align__(16) float xs[NTOP];   // 4 KB each
    __shared__ __align__(16) float ys[NTOP];
    __shared__ __align__(16) float zs[NTOP];
    __shared__ float pm[8 * 256];              // 8 KB per-wave partial mins
    __shared__ float wsum[8];

    const int t     = threadIdx.x;
    const int b     = blockIdx.x >> 6;      // batch
    const int chunk = blockIdx.x & 63;      // 256-point chunk
    const int w     = t >> 6;               // wave 0..7
    const int l     = t & 63;               // lane

    // ---- stage tops (j==15 slice) as SoA, no t2 ----
    const float* nmb = nm + b * NM_BATCH_STRIDE;
    #pragma unroll
    for (int p0 = 0; p0 < NTOP; p0 += NTHR) {
        const int p = p0 + t;
        const int i = p >> 5, k = p & 31;
        const int base = i * 512 + 480 + k;          // (i*16+15)*32 + k
        xs[p] = nmb[0 * CH_STRIDE + base];
        ys[p] = nmb[1 * CH_STRIDE + base];
        zs[p] = nmb[2 * CH_STRIDE + base];
    }

    // ---- this lane's 4 points (same 4 points in every wave) ----
    const float* pcb = pc + b * NM_BATCH_STRIDE;
    const int m0 = chunk * 256 + l;                  // point p_j = l + j*64
    float px2[4], py2[4], pz2[4], pp[4], mn[4];
    #pragma unroll
    for (int j = 0; j < 4; ++j) {
        const int m = m0 + j * 64;
        float x = pcb[m];
        float y = pcb[CH_STRIDE + m];
        float z = pcb[2 * CH_STRIDE + m];
        pp[j]  = x * x + y * y + z * z;
        px2[j] = -2.0f * x;
        py2[j] = -2.0f * y;
        pz2[j] = -2.0f * z;
        mn[j]  = FLT_MAX;
    }
    __syncthreads();

    // ---- wave w scans its 128-top share for all 4 points/lane ----
    const float4* xs4 = reinterpret_cast<const float4*>(xs);
    const float4* ys4 = reinterpret_cast<const float4*>(ys);
    const float4* zs4 = reinterpret_cast<const float4*>(zs);
    const int base4 = w * (TOPS_PER_WAVE / 4);       // float4 index of share

    #pragma unroll 2
    for (int g = 0; g < TOPS_PER_WAVE / 8; ++g) {
        float4 X0 = xs4[base4 + 2 * g];
        float4 X1 = xs4[base4 + 2 * g + 1];
        float4 Y0 = ys4[base4 + 2 * g];
        float4 Y1 = ys4[base4 + 2 * g + 1];
        float4 Z0 = zs4[base4 + 2 * g];
        float4 Z1 = zs4[base4 + 2 * g + 1];
        float tx[8] = {X0.x, X0.y, X0.z, X0.w, X1.x, X1.y, X1.z, X1.w};
        float ty[8] = {Y0.x, Y0.y, Y0.z, Y0.w, Y1.x, Y1.y, Y1.z, Y1.w};
        float tz[8] = {Z0.x, Z0.y, Z0.z, Z0.w, Z1.x, Z1.y, Z1.z, Z1.w};
        float t2[8];
        #pragma unroll
        for (int e = 0; e < 8; ++e)
            t2[e] = __builtin_fmaf(tx[e], tx[e],
                    __builtin_fmaf(ty[e], ty[e], tz[e] * tz[e]));
        #pragma unroll
        for (int j = 0; j < 4; ++j) {
            #define DISTD(e) __builtin_fmaf(px2[j], tx[e], \
                             __builtin_fmaf(py2[j], ty[e], \
                             __builtin_fmaf(pz2[j], tz[e], t2[e])))
            float d0 = DISTD(0);
            float d1 = DISTD(1);
            float d2 = DISTD(2);
            float d3 = DISTD(3);
            float d4 = DISTD(4);
            float d5 = DISTD(5);
            float d6 = DISTD(6);
            float d7 = DISTD(7);
            #undef DISTD
            mn[j] = fminf(mn[j], fminf(d0, d1));   // v_min3_f32
            mn[j] = fminf(mn[j], fminf(d2, d3));
            mn[j] = fminf(mn[j], fminf(d4, d5));
            mn[j] = fminf(mn[j], fminf(d6, d7));
        }
    }

    // ---- per-wave partial (+|p|^2, commutes with cross-wave min) ----
    #pragma unroll
    for (int j = 0; j < 4; ++j)
        pm[w * 256 + l + j * 64] = mn[j] + pp[j];
    __syncthreads();

    // ---- 8-way min combine (threads 0..255) ----
    float v = 0.0f;
    if (t < 256) {
        float d = pm[t];
        #pragma unroll
        for (int ww = 1; ww < 8; ++ww)
            d = fminf(d, pm[ww * 256 + t]);
        v = d * (1.0f / 65536.0f);
    }

    // ---- fem MSE slice: 180 float4 pairs per block ----
    if (t < FEM_PER_BLK) {
        const int q   = blockIdx.x * FEM_PER_BLK + t;   // < 46080
        const int bci = q / 120;
        const int r   = q - bci * 120;
        const int s   = bci * 128 + r;
        float4 a = reinterpret_cast<const float4*>(nm)[s];
        float4 f = reinterpret_cast<const float4*>(fem)[s];
        float dx = a.x - f.x, dy = a.y - f.y, dz = a.z - f.z, dw = a.w - f.w;
        v += (dx * dx + dy * dy + dz * dz + dw * dw) * (1.0f / 184320.0f);
    }

    // ---- block reduce (8 waves) + plain store of block partial ----
    for (int o = 32; o > 0; o >>= 1) v += __shfl_down(v, o, 64);
    if (l == 0) wsum[w] = v;
    __syncthreads();
    if (t == 0) {
        float s = 0.0f;
        #pragma unroll
        for (int ww = 0; ww < 8; ++ww) s += wsum[ww];
        ws[blockIdx.x] = s;
    }
}

__global__ __launch_bounds__(64) void meshloss_final(
    const float* __restrict__ ws, float* __restrict__ out)
{
    const float4 a = reinterpret_cast<const float4*>(ws)[threadIdx.x];
    float v = (a.x + a.y) + (a.z + a.w);
    for (int o = 32; o > 0; o >>= 1) v += __shfl_down(v, o, 64);
    if (threadIdx.x == 0) out[0] = v;
}

extern "C" void kernel_launch(void* const* d_in, const int* in_sizes, int n_in,
                              void* d_out, int out_size, void* d_ws, size_t ws_size,
                              hipStream_t stream) {
    const float* nm  = (const float*)d_in[0];
    const float* pc  = (const float*)d_in[1];
    const float* fem = (const float*)d_in[2];
    float* out = (float*)d_out;
    float* ws  = (float*)d_ws;

    meshloss_fused<<<NBLK, NTHR, 0, stream>>>(nm, pc, fem, ws);
    meshloss_final<<<1, 64, 0, stream>>>(ws, out);
}